// Round 4
// baseline (1478.854 us; speedup 1.0000x reference)
//
#include <hip/hip_runtime.h>
#include <hip/hip_fp16.h>
#include <cmath>

// B=2, H=8, S=4096, d=64; fp32 in/out.
// e = (Q@K)/sqrt(512); a = softmax over HEADS; o = a@V.
//
// R11: sum-only LDS exchange. R10's bottleneck was the EA score round-trip
// through LDS (34 LDS ops + 32 cvts per thread per tile, 2 barriers, lockstep).
// New scheme per wave (= head), BM=16 q-rows:
//  - swapped QK^T with kperm (R9-verified): mfma(kf_perm, qf) -> lane holds
//    raw f32 scores at (s=l15, t=8*quad+j) == PV A-frag layout exactly.
//  - exp2 in-register on raw f32 scores (Kt pre-scaled by scale*log2e).
//  - cross-head coupling via f32 LDS atomics ONLY: atomicAdd 8 exps into
//    SUM[s][t] (pitch 33 -> 2-way bank, free). Scores never hit LDS.
//  - 4-buffer SUM rotation: phase A(it) = {adds->SUM[it&3], PV(it-1) reads
//    SUM[(it-1)&3], zero SUM[(it+2)&3]}; every hazard barrier-separated ->
//    ONE barrier per tile (was 2).
//  - PV: read 8 sums, rcp, scale exps, pack bf16 -> mfma(pf, vf).
// LDS ops 34->17/thread/tile, -32 cvts, LDS 40960->8448B. Numerics improve
// (f32 scores+sums; only P rounded to bf16).
#define S_LEN 4096
#define NHEAD 8
#define HEADD 64
#define BM 16
#define BN 32
#define TSPLIT 4
#define TCHUNK (S_LEN / TSPLIT)      // 1024 keys per combo
#define NTILE (TCHUNK / BN)          // 32 iterations
#define KPRE 0.0637588696f           // (1/sqrt(512)) * log2(e)

#define KT_BYTES (2ull * NHEAD * S_LEN * HEADD * 2)        // 8,388,608 bf16 K^T [t][k]
#define VT_OFF   KT_BYTES
#define PART_OFF (2 * KT_BYTES)                             // 16,777,216
#define PART_BYTES (8ull * NHEAD * (S_LEN / 2) * HEADD * 4) // 33,554,432 (8 combos)
#define WS_FULL  (PART_OFF + PART_BYTES)                    // 50,331,648

typedef __attribute__((ext_vector_type(8))) short   short8;
typedef __attribute__((ext_vector_type(4))) float   float4v;
typedef __attribute__((ext_vector_type(2))) float   float2v;

__device__ __forceinline__ unsigned short f2bf(float f) {  // fp32 -> bf16 RNE
  unsigned int u = __float_as_uint(f);
  u += 0x7FFFu + ((u >> 16) & 1u);
  return (unsigned short)(u >> 16);
}

__device__ __forceinline__ unsigned int pkbf(float lo, float hi) {  // 2xfp32 -> packed bf16
  return __builtin_amdgcn_perm(__float_as_uint(hi) + 0x8000u,
                               __float_as_uint(lo) + 0x8000u, 0x07060302u);
}

// ---------------- pre-pass: LDS-free, float4 reads, in-register 8x4 transpose,
// b128 global writes. 1024 blocks x 256 thr (512 K-blocks, 512 V-blocks).
// K [bh,64,4096] f32 -> Kt [bh,4096,64] bf16*KPRE ; V [bh,4096,64] f32 -> Vt [bh,64,4096] bf16
__global__ __launch_bounds__(256)
void prepass_cvt(const float* __restrict__ K, const float* __restrict__ V,
                 unsigned short* __restrict__ Kt, unsigned short* __restrict__ Vt) {
  const int tid  = threadIdx.x;
  const int wave = tid >> 6, lane = tid & 63;
  const int isV  = blockIdx.x >> 9;
  const int idx  = blockIdx.x & 511;
  const int bh   = idx >> 5;                       // 16 bh
  const int t0   = (idx & 31) * 128 + wave * 32;   // block covers 128 t; wave covers 32 t
  if (!isV) {
    const float* in = K + (size_t)bh * HEADD * S_LEN;       // [k][t]
    unsigned short* out = Kt + (size_t)bh * S_LEN * HEADD;  // [t][k]
    const int koct = lane >> 3;          // k = koct*8 + j
    const int kt4  = (lane & 7) * 4;     // 4 t per lane
    float buf[8][4];
#pragma unroll
    for (int j = 0; j < 8; ++j) {
      float4v v = *(const float4v*)(in + (size_t)(koct * 8 + j) * S_LEN + t0 + kt4);
      buf[j][0] = v[0]; buf[j][1] = v[1]; buf[j][2] = v[2]; buf[j][3] = v[3];
    }
#pragma unroll
    for (int c = 0; c < 4; ++c) {
      short8 f;
#pragma unroll
      for (int j = 0; j < 8; ++j) f[j] = (short)f2bf(buf[j][c] * KPRE);
      *(short8*)(out + (size_t)(t0 + kt4 + c) * HEADD + koct * 8) = f;
    }
  } else {
    const float* in = V + (size_t)bh * S_LEN * HEADD;       // [t][d]
    unsigned short* out = Vt + (size_t)bh * HEADD * S_LEN;  // [d][t]
    const int vdq = lane & 15;           // d = vdq*4 + c
    const int vtg = lane >> 4;           // t = t0 + vtg*8 + j
    float buf[8][4];
#pragma unroll
    for (int j = 0; j < 8; ++j) {
      float4v v = *(const float4v*)(in + (size_t)(t0 + vtg * 8 + j) * HEADD + vdq * 4);
      buf[j][0] = v[0]; buf[j][1] = v[1]; buf[j][2] = v[2]; buf[j][3] = v[3];
    }
#pragma unroll
    for (int c = 0; c < 4; ++c) {
      short8 f;
#pragma unroll
      for (int j = 0; j < 8; ++j) f[j] = (short)f2bf(buf[j][c]);
      *(short8*)(out + (size_t)(vdq * 4 + c) * S_LEN + t0 + vtg * 8) = f;
    }
  }
}

// ---------------- main: 2048 blocks x 512 thr (8 waves, wave=head), BM=16 q-rows.
// combo = blockIdx&7: XCD-pinned (b,tc); each XCD's L2 holds its 2MB K/V slice.
__global__ __launch_bounds__(512, 4)
void attn_main(const float* __restrict__ Q, const unsigned short* __restrict__ Kt,
               const unsigned short* __restrict__ Vt, unsigned int* __restrict__ part) {
  // f32 sums, pitch 33: bank = (l15 + 8q + j + 16b)%32 -> <=2-way (free).
  __shared__ __align__(16) float SUM[4][BM][33];             // 8448 B
  float* sf = &SUM[0][0][0];                                 // 2112 floats

  const int tid  = threadIdx.x;
  const int h    = tid >> 6;
  const int lane = tid & 63;
  const int quad = lane >> 4;
  const int l15  = lane & 15;
  const int combo = blockIdx.x & 7;
  const int b  = combo & 1;
  const int tc = combo >> 1;
  const int s0 = (blockIdx.x >> 3) * BM;
  const int tbase = tc * TCHUNK;
  // A-frag m-row -> K-row offset so score slot (quad, grp*4+r) holds t = 8*quad + grp*4+r
  const int kperm = ((l15 >> 2) << 3) + (l15 & 3);

  const float* Qg = Q + (size_t)(b * NHEAD + h) * S_LEN * HEADD;
  const unsigned short* Kth = Kt + (size_t)(b * NHEAD + h) * S_LEN * HEADD;  // [t][k]
  const unsigned short* Vth = Vt + (size_t)(b * NHEAD + h) * HEADD * S_LEN;  // [d][t]

  // Q B-frag: n=l15 (s-row), k = kk*32 + quad*8 + j (d)
  short8 qf[2];
#pragma unroll
  for (int kk = 0; kk < 2; ++kk) {
    const float* p = Qg + (size_t)(s0 + l15) * HEADD + kk * 32 + quad * 8;
    float4v a0 = *(const float4v*)p;
    float4v a1 = *(const float4v*)(p + 4);
    short8 f;
    f[0] = (short)f2bf(a0[0]); f[1] = (short)f2bf(a0[1]);
    f[2] = (short)f2bf(a0[2]); f[3] = (short)f2bf(a0[3]);
    f[4] = (short)f2bf(a1[0]); f[5] = (short)f2bf(a1[1]);
    f[6] = (short)f2bf(a1[2]); f[7] = (short)f2bf(a1[3]);
    qf[kk] = f;
  }

  // acc[df] = o[s = s0 + quad*4 + r][d = df*16 + l15]
  float4v acc[4];
#pragma unroll
  for (int df = 0; df < 4; ++df) acc[df] = (float4v){0.f, 0.f, 0.f, 0.f};

  // zero all 4 SUM buffers
  sf[tid] = 0.f; sf[tid + 512] = 0.f; sf[tid + 1024] = 0.f; sf[tid + 1536] = 0.f;
  if (tid < 64) sf[tid + 2048] = 0.f;
  __syncthreads();

  float ex[8];   // exps of current tile, carried across the barrier

  // ---- tile 0: QK^T + exp + adds -> SUM[0] ----
  {
    const int t0 = tbase;
    const unsigned short* Kp = Kth + (size_t)(t0 + kperm) * HEADD + quad * 8;
    short8 k00 = *(const short8*)(Kp);
    short8 k01 = *(const short8*)(Kp + 32);
    short8 k10 = *(const short8*)(Kp + 4 * HEADD);
    short8 k11 = *(const short8*)(Kp + 4 * HEADD + 32);
    float4v e0 = (float4v){0.f, 0.f, 0.f, 0.f};
    float4v e1 = (float4v){0.f, 0.f, 0.f, 0.f};
    e0 = __builtin_amdgcn_mfma_f32_16x16x32_bf16(k00, qf[0], e0, 0, 0, 0);
    e0 = __builtin_amdgcn_mfma_f32_16x16x32_bf16(k01, qf[1], e0, 0, 0, 0);
    e1 = __builtin_amdgcn_mfma_f32_16x16x32_bf16(k10, qf[0], e1, 0, 0, 0);
    e1 = __builtin_amdgcn_mfma_f32_16x16x32_bf16(k11, qf[1], e1, 0, 0, 0);
#pragma unroll
    for (int r = 0; r < 4; ++r) { ex[r] = exp2f(e0[r]); ex[4 + r] = exp2f(e1[r]); }
#pragma unroll
    for (int j = 0; j < 8; ++j) atomicAdd(&SUM[0][l15][quad * 8 + j], ex[j]);
  }
  __syncthreads();

  // ---- main loop: ONE barrier per tile ----
  for (int it = 1; it < NTILE; ++it) {
    const int tcur = tbase + it * BN;
    const int tprv = tcur - BN;
    const int bcur = it & 3, bprv = (it - 1) & 3, bzro = (it + 2) & 3;

    // issue K loads (cur) + V loads (prev) + sum reads (prev) early
    const unsigned short* Kp = Kth + (size_t)(tcur + kperm) * HEADD + quad * 8;
    short8 k00 = *(const short8*)(Kp);
    short8 k01 = *(const short8*)(Kp + 32);
    short8 k10 = *(const short8*)(Kp + 4 * HEADD);
    short8 k11 = *(const short8*)(Kp + 4 * HEADD + 32);
    short8 vf[4];
#pragma unroll
    for (int df = 0; df < 4; ++df)
      vf[df] = *(const short8*)(Vth + (size_t)(df * 16 + l15) * S_LEN + tprv + quad * 8);
    float sm[8];
#pragma unroll
    for (int j = 0; j < 8; ++j) sm[j] = SUM[bprv][l15][quad * 8 + j];

    // zero the buffer 2 tiles ahead (read last phase; next adds 2 phases out)
    if (tid < 264) *(float2v*)(sf + bzro * 528 + tid * 2) = (float2v){0.f, 0.f};

    // PV(it-1): normalize carried exps, pack bf16, mfma
    short8 pf;
    {
      unsigned int* pu = (unsigned int*)&pf;
#pragma unroll
      for (int i = 0; i < 4; ++i) {
        float lo = ex[2 * i]     * __builtin_amdgcn_rcpf(sm[2 * i]);
        float hi = ex[2 * i + 1] * __builtin_amdgcn_rcpf(sm[2 * i + 1]);
        pu[i] = pkbf(lo, hi);
      }
    }
#pragma unroll
    for (int df = 0; df < 4; ++df)
      acc[df] = __builtin_amdgcn_mfma_f32_16x16x32_bf16(pf, vf[df], acc[df], 0, 0, 0);

    // QK^T(it) + exp + adds
    float4v e0 = (float4v){0.f, 0.f, 0.f, 0.f};
    float4v e1 = (float4v){0.f, 0.f, 0.f, 0.f};
    e0 = __builtin_amdgcn_mfma_f32_16x16x32_bf16(k00, qf[0], e0, 0, 0, 0);
    e0 = __builtin_amdgcn_mfma_f32_16x16x32_bf16(k01, qf[1], e0, 0, 0, 0);
    e1 = __builtin_amdgcn_mfma_f32_16x16x32_bf16(k10, qf[0], e1, 0, 0, 0);
    e1 = __builtin_amdgcn_mfma_f32_16x16x32_bf16(k11, qf[1], e1, 0, 0, 0);
#pragma unroll
    for (int r = 0; r < 4; ++r) { ex[r] = exp2f(e0[r]); ex[4 + r] = exp2f(e1[r]); }
#pragma unroll
    for (int j = 0; j < 8; ++j) atomicAdd(&SUM[bcur][l15][quad * 8 + j], ex[j]);

    __syncthreads();
  }

  // ---- epilogue: PV(NTILE-1) ----
  {
    const int tprv = tbase + (NTILE - 1) * BN;
    const int bprv = (NTILE - 1) & 3;
    short8 vf[4];
#pragma unroll
    for (int df = 0; df < 4; ++df)
      vf[df] = *(const short8*)(Vth + (size_t)(df * 16 + l15) * S_LEN + tprv + quad * 8);
    short8 pf;
    unsigned int* pu = (unsigned int*)&pf;
#pragma unroll
    for (int i = 0; i < 4; ++i) {
      float lo = ex[2 * i]     * __builtin_amdgcn_rcpf(SUM[bprv][l15][quad * 8 + 2 * i]);
      float hi = ex[2 * i + 1] * __builtin_amdgcn_rcpf(SUM[bprv][l15][quad * 8 + 2 * i + 1]);
      pu[i] = pkbf(lo, hi);
    }
#pragma unroll
    for (int df = 0; df < 4; ++df)
      acc[df] = __builtin_amdgcn_mfma_f32_16x16x32_bf16(pf, vf[df], acc[df], 0, 0, 0);
  }

  // ---- partials: packed bf16 s-pairs, layout [combo(8)][h][sp(2048)][d(64)] ----
  unsigned int* pb = part + ((size_t)combo * NHEAD + h) * (2048ull * 64);
  const int spb = (s0 >> 1) + quad * 2;
#pragma unroll
  for (int df = 0; df < 4; ++df)
#pragma unroll
    for (int rp = 0; rp < 2; ++rp) {
      unsigned int ulo = __float_as_uint(acc[df][rp * 2])     + 0x8000u;
      unsigned int uhi = __float_as_uint(acc[df][rp * 2 + 1]) + 0x8000u;
      unsigned int pk  = __builtin_amdgcn_perm(uhi, ulo, 0x07060302u);
      pb[(size_t)(spb + rp) * 64 + df * 16 + l15] = pk;
    }
}

// ---------------- reduce: sum 4 tc-partials (packed bf16 s-pairs) -> fp32 O ----------------
// part: [c=tc*2+b (8)][h (8)][sp (2048)][d (64)] u32. 8192 blocks x 256 thr.
// OUTPUT ORDER IS RAW [B,H,S,d] CONTIGUOUS (torch .view(B,S,512) is a reinterpret).
__global__ __launch_bounds__(256)
void reduce_partials(const unsigned int* __restrict__ part, float* __restrict__ out) {
  const size_t tid = (size_t)blockIdx.x * 256 + threadIdx.x;   // 2,097,152 total
  const unsigned int d  = (unsigned int)(tid & 63);
  const unsigned int h  = (unsigned int)((tid >> 6) & 7);
  const unsigned int sp = (unsigned int)((tid >> 9) & 2047);
  const unsigned int b  = (unsigned int)(tid >> 20);
  float lo = 0.f, hi = 0.f;
#pragma unroll
  for (int tcc = 0; tcc < 4; ++tcc) {
    unsigned int v = part[(((size_t)(tcc * 2 + b) * NHEAD + h) * (S_LEN / 2) + sp) * HEADD + d];
    lo += __uint_as_float(v << 16);
    hi += __uint_as_float(v & 0xffff0000u);
  }
  float* o = out + (((size_t)(b * NHEAD + h)) * S_LEN + 2 * sp) * HEADD + d;
  o[0]     = lo;
  o[HEADD] = hi;   // s = 2*sp + 1
}

// ---------------- zero-workspace fallback (round-1 kernel, known correct) ----------------
__global__ __launch_bounds__(512, 2)
void attn_fallback(const float* __restrict__ Qg0, const float* __restrict__ Kg0,
                   const float* __restrict__ Vg0, float* __restrict__ Og0) {
  __shared__ __align__(16) unsigned short Klds[NHEAD][32][72];
  __shared__ __align__(16) unsigned short Vlds[NHEAD][HEADD][40];
  __shared__ __align__(16) unsigned short EA2[NHEAD][64][40];
  const int tid = threadIdx.x, h = tid >> 6, lane = tid & 63, quad = lane >> 4, l15 = lane & 15;
  const int b = blockIdx.x >> 6, s0 = (blockIdx.x & 63) * 64;
  const float* Qg = Qg0 + ((size_t)(b * NHEAD + h)) * S_LEN * HEADD;
  const float* Kg = Kg0 + ((size_t)(b * NHEAD + h)) * HEADD * S_LEN;
  const float* Vg = Vg0 + ((size_t)(b * NHEAD + h)) * S_LEN * HEADD;
  float* Og = Og0 + ((size_t)(b * NHEAD + h)) * S_LEN * HEADD;
  const float SC = 0.04419417382415922f;
  short8 qf[4][2];
#pragma unroll
  for (int ss = 0; ss < 4; ++ss)
#pragma unroll
    for (int kk = 0; kk < 2; ++kk) {
      const float* p = Qg + (size_t)(s0 + ss * 16 + l15) * HEADD + kk * 32 + quad * 8;
      float4v a0 = *(const float4v*)p; float4v a1 = *(const float4v*)(p + 4);
      short8 f;
      f[0] = (short)f2bf(a0[0]); f[1] = (short)f2bf(a0[1]); f[2] = (short)f2bf(a0[2]); f[3] = (short)f2bf(a0[3]);
      f[4] = (short)f2bf(a1[0]); f[5] = (short)f2bf(a1[1]); f[6] = (short)f2bf(a1[2]); f[7] = (short)f2bf(a1[3]);
      qf[ss][kk] = f;
    }
  float4v acc[4][4];
#pragma unroll
  for (int ss = 0; ss < 4; ++ss)
#pragma unroll
    for (int ds = 0; ds < 4; ++ds) acc[ss][ds] = (float4v){0.f, 0.f, 0.f, 0.f};
  const int koct = lane >> 3, kt4 = (lane & 7) * 4, vdq = lane & 15, vtg = lane >> 4;
  const int s_sm = tid >> 3, t4_sm = (tid & 7) * 4;
  for (int it = 0; it < S_LEN / 32; ++it) {
    const int t0 = it * 32;
    {
      float buf[8][4];
#pragma unroll
      for (int j = 0; j < 8; ++j) {
        float4v v = *(const float4v*)(Kg + (size_t)(koct * 8 + j) * S_LEN + t0 + kt4);
        buf[j][0] = v[0]; buf[j][1] = v[1]; buf[j][2] = v[2]; buf[j][3] = v[3];
      }
#pragma unroll
      for (int c = 0; c < 4; ++c) {
        short8 f;
#pragma unroll
        for (int j = 0; j < 8; ++j) f[j] = (short)f2bf(buf[j][c]);
        *(short8*)&Klds[h][kt4 + c][koct * 8] = f;
      }
    }
    {
      float buf[8][4];
#pragma unroll
      for (int j = 0; j < 8; ++j) {
        float4v v = *(const float4v*)(Vg + (size_t)(t0 + vtg * 8 + j) * HEADD + vdq * 4);
        buf[j][0] = v[0]; buf[j][1] = v[1]; buf[j][2] = v[2]; buf[j][3] = v[3];
      }
#pragma unroll
      for (int c = 0; c < 4; ++c) {
        short8 f;
#pragma unroll
        for (int j = 0; j < 8; ++j) f[j] = (short)f2bf(buf[j][c]);
        *(short8*)&Vlds[h][vdq * 4 + c][vtg * 8] = f;
      }
    }
    __syncthreads();
#pragma unroll
    for (int ts = 0; ts < 2; ++ts) {
      short8 kf0 = *(const short8*)&Klds[h][ts * 16 + l15][quad * 8];
      short8 kf1 = *(const short8*)&Klds[h][ts * 16 + l15][32 + quad * 8];
#pragma unroll
      for (int ss = 0; ss < 4; ++ss) {
        float4v e = (float4v){0.f, 0.f, 0.f, 0.f};
        e = __builtin_amdgcn_mfma_f32_16x16x32_bf16(qf[ss][0], kf0, e, 0, 0, 0);
        e = __builtin_amdgcn_mfma_f32_16x16x32_bf16(qf[ss][1], kf1, e, 0, 0, 0);
#pragma unroll
        for (int r = 0; r < 4; ++r)
          EA2[h][ss * 16 + quad * 4 + r][ts * 16 + l15] = __half_as_ushort(__float2half(e[r] * SC));
      }
    }
    __syncthreads();
    {
      float ev[8][4];
#pragma unroll
      for (int hh = 0; hh < 8; ++hh) {
        unsigned long long u = *(const unsigned long long*)&EA2[hh][s_sm][t4_sm];
        ev[hh][0] = __half2float(__ushort_as_half((unsigned short)u));
        ev[hh][1] = __half2float(__ushort_as_half((unsigned short)(u >> 16)));
        ev[hh][2] = __half2float(__ushort_as_half((unsigned short)(u >> 32)));
        ev[hh][3] = __half2float(__ushort_as_half((unsigned short)(u >> 48)));
      }
#pragma unroll
      for (int c = 0; c < 4; ++c) {
        float m = ev[0][c];
#pragma unroll
        for (int hh = 1; hh < 8; ++hh) m = fmaxf(m, ev[hh][c]);
        float sum = 0.f;
#pragma unroll
        for (int hh = 0; hh < 8; ++hh) { float x = __expf(ev[hh][c] - m); ev[hh][c] = x; sum += x; }
        float inv = __builtin_amdgcn_rcpf(sum);
#pragma unroll
        for (int hh = 0; hh < 8; ++hh) ev[hh][c] *= inv;
      }
#pragma unroll
      for (int hh = 0; hh < 8; ++hh) {
        unsigned short u0 = f2bf(ev[hh][0]), u1 = f2bf(ev[hh][1]), u2 = f2bf(ev[hh][2]), u3 = f2bf(ev[hh][3]);
        unsigned long long w = (unsigned long long)u0 | ((unsigned long long)u1 << 16) |
                               ((unsigned long long)u2 << 32) | ((unsigned long long)u3 << 48);
        *(unsigned long long*)&EA2[hh][s_sm][t4_sm] = w;
      }
    }
    __syncthreads();
    {
      short8 af[4], vf[4];
#pragma unroll
      for (int ss = 0; ss < 4; ++ss) af[ss] = *(const short8*)&EA2[h][ss * 16 + l15][quad * 8];
#pragma unroll
      for (int ds = 0; ds < 4; ++ds) vf[ds] = *(const short8*)&Vlds[h][ds * 16 + l15][quad * 8];
#pragma unroll
      for (int ss = 0; ss < 4; ++ss)
#pragma unroll
        for (int ds = 0; ds < 4; ++ds)
          acc[ss][ds] = __builtin_amdgcn_mfma_f32_16x16x32_bf16(af[ss], vf[ds], acc[ss][ds], 0, 0, 0);
    }
    __syncthreads();
  }
#pragma unroll
  for (int ss = 0; ss < 4; ++ss)
#pragma unroll
    for (int ds = 0; ds < 4; ++ds)
#pragma unroll
      for (int r = 0; r < 4; ++r)
        Og[(size_t)(s0 + ss * 16 + quad * 4 + r) * HEADD + ds * 16 + l15] = acc[ss][ds][r];
}

extern "C" void kernel_launch(void* const* d_in, const int* in_sizes, int n_in,
                              void* d_out, int out_size, void* d_ws, size_t ws_size,
                              hipStream_t stream) {
  const float* Q = (const float*)d_in[0];
  const float* K = (const float*)d_in[1];
  const float* V = (const float*)d_in[2];
  float* O = (float*)d_out;

  if (ws_size >= WS_FULL) {
    unsigned short* Kt = (unsigned short*)d_ws;
    unsigned short* Vt = (unsigned short*)((char*)d_ws + VT_OFF);
    unsigned int* part = (unsigned int*)((char*)d_ws + PART_OFF);
    hipLaunchKernelGGL(prepass_cvt, dim3(1024), dim3(256), 0, stream, K, V, Kt, Vt);
    hipLaunchKernelGGL(attn_main, dim3(2048), dim3(512), 0, stream, Q, Kt, Vt, part);
    hipLaunchKernelGGL(reduce_partials, dim3(8192), dim3(256), 0, stream, part, O);
  } else {
    hipLaunchKernelGGL(attn_fallback, dim3(128), dim3(512), 0, stream, Q, K, V, O);
  }
}

// Round 5
// 558.755 us; speedup vs baseline: 2.6467x; 2.6467x over previous
//
#include <hip/hip_runtime.h>
#include <hip/hip_fp16.h>
#include <cmath>

// B=2, H=8, S=4096, d=64; fp32 in/out.
// e = (Q@K)/sqrt(512); a = softmax over HEADS; o = a@V.
//
// R12: f32 exp-exchange, one barrier per tile, zero f16 round-trip.
//  - wave = head, BM=16 q-rows, swapped QK^T + kperm (R11-verified): lane
//    holds raw f32 scores at (s=l15, t=8q+j) == PV A-frag layout.
//  - Phase A(it): QK^T + exp2 in-register; write 8 exps as 2x ds_write_b128
//    into EW[it&1][h][s][c], c = t ^ ((s&7)<<2) XOR-swizzle (bank-balanced).
//  - ONE barrier.
//  - Phase B(it): thread owns one (s,t) slot: 8x b32 reads (2-way, free) sum
//    all heads -> Z[it&1][s][t]; read Z[(it-1)&1] (2x b128) to normalize the
//    CARRIED exps of tile it-1 -> pf -> PV(it-1). EW/Z double-buffered: every
//    conflicting pair is barrier-separated (checked pairwise).
// R11 lesson: LDS atomics serialize (8.4e6 conflict cycles, 1425us) -- the
// sum is now plain reads distributed over 512 threads. R7 lesson: the f16
// score round-trip (34-40 LDS ops + 32 cvts/thread/tile) was the path.
#define S_LEN 4096
#define NHEAD 8
#define HEADD 64
#define BM 16
#define BN 32
#define TSPLIT 4
#define TCHUNK (S_LEN / TSPLIT)      // 1024 keys per combo
#define NTILE (TCHUNK / BN)          // 32 iterations
#define KPRE 0.0637588696f           // (1/sqrt(512)) * log2(e)

#define KT_BYTES (2ull * NHEAD * S_LEN * HEADD * 2)        // 8,388,608 bf16 K^T [t][k]
#define VT_OFF   KT_BYTES
#define PART_OFF (2 * KT_BYTES)                             // 16,777,216
#define PART_BYTES (8ull * NHEAD * (S_LEN / 2) * HEADD * 4) // 33,554,432 (8 combos)
#define WS_FULL  (PART_OFF + PART_BYTES)                    // 50,331,648

typedef __attribute__((ext_vector_type(8))) short   short8;
typedef __attribute__((ext_vector_type(4))) float   float4v;

__device__ __forceinline__ unsigned short f2bf(float f) {  // fp32 -> bf16 RNE
  unsigned int u = __float_as_uint(f);
  u += 0x7FFFu + ((u >> 16) & 1u);
  return (unsigned short)(u >> 16);
}

__device__ __forceinline__ unsigned int pkbf(float lo, float hi) {  // 2xfp32 -> packed bf16
  return __builtin_amdgcn_perm(__float_as_uint(hi) + 0x8000u,
                               __float_as_uint(lo) + 0x8000u, 0x07060302u);
}

// ---------------- pre-pass: LDS-free, float4 reads, in-register 8x4 transpose,
// b128 global writes. 1024 blocks x 256 thr (512 K-blocks, 512 V-blocks).
// K [bh,64,4096] f32 -> Kt [bh,4096,64] bf16*KPRE ; V [bh,4096,64] f32 -> Vt [bh,64,4096] bf16
__global__ __launch_bounds__(256)
void prepass_cvt(const float* __restrict__ K, const float* __restrict__ V,
                 unsigned short* __restrict__ Kt, unsigned short* __restrict__ Vt) {
  const int tid  = threadIdx.x;
  const int wave = tid >> 6, lane = tid & 63;
  const int isV  = blockIdx.x >> 9;
  const int idx  = blockIdx.x & 511;
  const int bh   = idx >> 5;                       // 16 bh
  const int t0   = (idx & 31) * 128 + wave * 32;   // block covers 128 t; wave covers 32 t
  if (!isV) {
    const float* in = K + (size_t)bh * HEADD * S_LEN;       // [k][t]
    unsigned short* out = Kt + (size_t)bh * S_LEN * HEADD;  // [t][k]
    const int koct = lane >> 3;          // k = koct*8 + j
    const int kt4  = (lane & 7) * 4;     // 4 t per lane
    float buf[8][4];
#pragma unroll
    for (int j = 0; j < 8; ++j) {
      float4v v = *(const float4v*)(in + (size_t)(koct * 8 + j) * S_LEN + t0 + kt4);
      buf[j][0] = v[0]; buf[j][1] = v[1]; buf[j][2] = v[2]; buf[j][3] = v[3];
    }
#pragma unroll
    for (int c = 0; c < 4; ++c) {
      short8 f;
#pragma unroll
      for (int j = 0; j < 8; ++j) f[j] = (short)f2bf(buf[j][c] * KPRE);
      *(short8*)(out + (size_t)(t0 + kt4 + c) * HEADD + koct * 8) = f;
    }
  } else {
    const float* in = V + (size_t)bh * S_LEN * HEADD;       // [t][d]
    unsigned short* out = Vt + (size_t)bh * HEADD * S_LEN;  // [d][t]
    const int vdq = lane & 15;           // d = vdq*4 + c
    const int vtg = lane >> 4;           // t = t0 + vtg*8 + j
    float buf[8][4];
#pragma unroll
    for (int j = 0; j < 8; ++j) {
      float4v v = *(const float4v*)(in + (size_t)(t0 + vtg * 8 + j) * HEADD + vdq * 4);
      buf[j][0] = v[0]; buf[j][1] = v[1]; buf[j][2] = v[2]; buf[j][3] = v[3];
    }
#pragma unroll
    for (int c = 0; c < 4; ++c) {
      short8 f;
#pragma unroll
      for (int j = 0; j < 8; ++j) f[j] = (short)f2bf(buf[j][c]);
      *(short8*)(out + (size_t)(vdq * 4 + c) * S_LEN + t0 + vtg * 8) = f;
    }
  }
}

// ---------------- main: 2048 blocks x 512 thr (8 waves, wave=head), BM=16 q-rows.
// combo = blockIdx&7: XCD-pinned (b,tc); each XCD's L2 holds its 2MB K/V slice.
__global__ __launch_bounds__(512, 6)
void attn_main(const float* __restrict__ Q, const unsigned short* __restrict__ Kt,
               const unsigned short* __restrict__ Vt, unsigned int* __restrict__ part) {
  // EW[p][h][s][c]: f32 exps, col c = t ^ ((s&7)<<2). Z[p][s][c]: head-sums.
  __shared__ __align__(16) float EW[2][NHEAD][BM][32];   // 32,768 B
  __shared__ __align__(16) float Zb[2][BM][32];          //  4,096 B

  const int tid  = threadIdx.x;
  const int h    = tid >> 6;
  const int lane = tid & 63;
  const int quad = lane >> 4;
  const int l15  = lane & 15;
  const int combo = blockIdx.x & 7;
  const int b  = combo & 1;
  const int tc = combo >> 1;
  const int s0 = (blockIdx.x >> 3) * BM;
  const int tbase = tc * TCHUNK;
  // A-frag row permutation: score slot (quad, grp*4+r) holds t = 8*quad + grp*4+r
  const int kperm = ((l15 >> 2) << 3) + (l15 & 3);
  const int swz   = (l15 & 7) << 2;        // row-XOR col swizzle (frag side)
  const int cb    = (quad * 8) ^ swz;      // b128 col base; ^4 gives second half

  const int s_sm = tid >> 5;               // sum-phase slot row 0..15
  const int t_sm = tid & 31;               // slot col 0..31
  const int cs   = t_sm ^ ((s_sm & 7) << 2);

  const float* Qg = Q + (size_t)(b * NHEAD + h) * S_LEN * HEADD;
  const unsigned short* Kth = Kt + (size_t)(b * NHEAD + h) * S_LEN * HEADD;  // [t][k]
  const unsigned short* Vth = Vt + (size_t)(b * NHEAD + h) * HEADD * S_LEN;  // [d][t]

  // Q B-frag: n=l15 (s-row), k = kk*32 + quad*8 + j (d)
  short8 qf[2];
#pragma unroll
  for (int kk = 0; kk < 2; ++kk) {
    const float* p = Qg + (size_t)(s0 + l15) * HEADD + kk * 32 + quad * 8;
    float4v a0 = *(const float4v*)p;
    float4v a1 = *(const float4v*)(p + 4);
    short8 f;
    f[0] = (short)f2bf(a0[0]); f[1] = (short)f2bf(a0[1]);
    f[2] = (short)f2bf(a0[2]); f[3] = (short)f2bf(a0[3]);
    f[4] = (short)f2bf(a1[0]); f[5] = (short)f2bf(a1[1]);
    f[6] = (short)f2bf(a1[2]); f[7] = (short)f2bf(a1[3]);
    qf[kk] = f;
  }

  // acc[df] = o[s = s0 + quad*4 + r][d = df*16 + l15]
  float4v acc[4];
#pragma unroll
  for (int df = 0; df < 4; ++df) acc[df] = (float4v){0.f, 0.f, 0.f, 0.f};

  float exC[8], exP[8];

  // ---- A(0): QK^T(0) + exp -> EW[0] ----
  {
    const unsigned short* Kp = Kth + (size_t)(tbase + kperm) * HEADD + quad * 8;
    short8 k00 = *(const short8*)(Kp);
    short8 k01 = *(const short8*)(Kp + 32);
    short8 k10 = *(const short8*)(Kp + 4 * HEADD);
    short8 k11 = *(const short8*)(Kp + 4 * HEADD + 32);
    float4v e0 = (float4v){0.f, 0.f, 0.f, 0.f};
    float4v e1 = (float4v){0.f, 0.f, 0.f, 0.f};
    e0 = __builtin_amdgcn_mfma_f32_16x16x32_bf16(k00, qf[0], e0, 0, 0, 0);
    e0 = __builtin_amdgcn_mfma_f32_16x16x32_bf16(k01, qf[1], e0, 0, 0, 0);
    e1 = __builtin_amdgcn_mfma_f32_16x16x32_bf16(k10, qf[0], e1, 0, 0, 0);
    e1 = __builtin_amdgcn_mfma_f32_16x16x32_bf16(k11, qf[1], e1, 0, 0, 0);
#pragma unroll
    for (int r = 0; r < 4; ++r) { exC[r] = exp2f(e0[r]); exC[4 + r] = exp2f(e1[r]); }
    float* ewr = &EW[0][h][l15][0];
    *(float4v*)(ewr + cb)       = (float4v){exC[0], exC[1], exC[2], exC[3]};
    *(float4v*)(ewr + (cb ^ 4)) = (float4v){exC[4], exC[5], exC[6], exC[7]};
  }
  __syncthreads();
  // ---- B(0): sum only ----
  {
    const float* ews = &EW[0][0][s_sm][cs];
    float a0 = ews[0] + ews[512], a1 = ews[1024] + ews[1536];
    float a2 = ews[2048] + ews[2560], a3 = ews[3072] + ews[3584];
    Zb[0][s_sm][cs] = (a0 + a1) + (a2 + a3);
#pragma unroll
    for (int j = 0; j < 8; ++j) exP[j] = exC[j];
  }

  for (int it = 1; it < NTILE; ++it) {
    const int p = it & 1;
    // ---- A(it): QK^T + exp -> EW[p] ----
    {
      const unsigned short* Kp = Kth + (size_t)(tbase + it * BN + kperm) * HEADD + quad * 8;
      short8 k00 = *(const short8*)(Kp);
      short8 k01 = *(const short8*)(Kp + 32);
      short8 k10 = *(const short8*)(Kp + 4 * HEADD);
      short8 k11 = *(const short8*)(Kp + 4 * HEADD + 32);
      float4v e0 = (float4v){0.f, 0.f, 0.f, 0.f};
      float4v e1 = (float4v){0.f, 0.f, 0.f, 0.f};
      e0 = __builtin_amdgcn_mfma_f32_16x16x32_bf16(k00, qf[0], e0, 0, 0, 0);
      e0 = __builtin_amdgcn_mfma_f32_16x16x32_bf16(k01, qf[1], e0, 0, 0, 0);
      e1 = __builtin_amdgcn_mfma_f32_16x16x32_bf16(k10, qf[0], e1, 0, 0, 0);
      e1 = __builtin_amdgcn_mfma_f32_16x16x32_bf16(k11, qf[1], e1, 0, 0, 0);
#pragma unroll
      for (int r = 0; r < 4; ++r) { exC[r] = exp2f(e0[r]); exC[4 + r] = exp2f(e1[r]); }
      float* ewr = &EW[p][h][l15][0];
      *(float4v*)(ewr + cb)       = (float4v){exC[0], exC[1], exC[2], exC[3]};
      *(float4v*)(ewr + (cb ^ 4)) = (float4v){exC[4], exC[5], exC[6], exC[7]};
    }
    __syncthreads();
    // ---- B(it): V prefetch, sum(it) -> Z[p], pf(it-1) from Z[p^1], PV(it-1) ----
    {
      short8 vf[4];
#pragma unroll
      for (int df = 0; df < 4; ++df)
        vf[df] = *(const short8*)(Vth + (size_t)(df * 16 + l15) * S_LEN
                                  + (tbase + (it - 1) * BN) + quad * 8);
      const float* ews = &EW[p][0][s_sm][cs];
      float a0 = ews[0] + ews[512], a1 = ews[1024] + ews[1536];
      float a2 = ews[2048] + ews[2560], a3 = ews[3072] + ews[3584];
      Zb[p][s_sm][cs] = (a0 + a1) + (a2 + a3);

      const float* zr = &Zb[p ^ 1][l15][0];
      float4v z0 = *(const float4v*)(zr + cb);
      float4v z1 = *(const float4v*)(zr + (cb ^ 4));
      short8 pf;
      unsigned int* pu = (unsigned int*)&pf;
      pu[0] = pkbf(exP[0] * __builtin_amdgcn_rcpf(z0[0]),
                   exP[1] * __builtin_amdgcn_rcpf(z0[1]));
      pu[1] = pkbf(exP[2] * __builtin_amdgcn_rcpf(z0[2]),
                   exP[3] * __builtin_amdgcn_rcpf(z0[3]));
      pu[2] = pkbf(exP[4] * __builtin_amdgcn_rcpf(z1[0]),
                   exP[5] * __builtin_amdgcn_rcpf(z1[1]));
      pu[3] = pkbf(exP[6] * __builtin_amdgcn_rcpf(z1[2]),
                   exP[7] * __builtin_amdgcn_rcpf(z1[3]));
#pragma unroll
      for (int df = 0; df < 4; ++df)
        acc[df] = __builtin_amdgcn_mfma_f32_16x16x32_bf16(pf, vf[df], acc[df], 0, 0, 0);
#pragma unroll
      for (int j = 0; j < 8; ++j) exP[j] = exC[j];
    }
  }

  // ---- tail: PV(NTILE-1) ----
  __syncthreads();
  {
    const int p = (NTILE - 1) & 1;
    short8 vf[4];
#pragma unroll
    for (int df = 0; df < 4; ++df)
      vf[df] = *(const short8*)(Vth + (size_t)(df * 16 + l15) * S_LEN
                                + (tbase + (NTILE - 1) * BN) + quad * 8);
    const float* zr = &Zb[p][l15][0];
    float4v z0 = *(const float4v*)(zr + cb);
    float4v z1 = *(const float4v*)(zr + (cb ^ 4));
    short8 pf;
    unsigned int* pu = (unsigned int*)&pf;
    pu[0] = pkbf(exP[0] * __builtin_amdgcn_rcpf(z0[0]),
                 exP[1] * __builtin_amdgcn_rcpf(z0[1]));
    pu[1] = pkbf(exP[2] * __builtin_amdgcn_rcpf(z0[2]),
                 exP[3] * __builtin_amdgcn_rcpf(z0[3]));
    pu[2] = pkbf(exP[4] * __builtin_amdgcn_rcpf(z1[0]),
                 exP[5] * __builtin_amdgcn_rcpf(z1[1]));
    pu[3] = pkbf(exP[6] * __builtin_amdgcn_rcpf(z1[2]),
                 exP[7] * __builtin_amdgcn_rcpf(z1[3]));
#pragma unroll
    for (int df = 0; df < 4; ++df)
      acc[df] = __builtin_amdgcn_mfma_f32_16x16x32_bf16(pf, vf[df], acc[df], 0, 0, 0);
  }

  // ---- partials: packed bf16 s-pairs, layout [combo(8)][h][sp(2048)][d(64)] ----
  unsigned int* pb = part + ((size_t)combo * NHEAD + h) * (2048ull * 64);
  const int spb = (s0 >> 1) + quad * 2;
#pragma unroll
  for (int df = 0; df < 4; ++df)
#pragma unroll
    for (int rp = 0; rp < 2; ++rp) {
      unsigned int ulo = __float_as_uint(acc[df][rp * 2])     + 0x8000u;
      unsigned int uhi = __float_as_uint(acc[df][rp * 2 + 1]) + 0x8000u;
      unsigned int pk  = __builtin_amdgcn_perm(uhi, ulo, 0x07060302u);
      pb[(size_t)(spb + rp) * 64 + df * 16 + l15] = pk;
    }
}

// ---------------- reduce: sum 4 tc-partials (packed bf16 s-pairs) -> fp32 O ----------------
// part: [c=tc*2+b (8)][h (8)][sp (2048)][d (64)] u32. 8192 blocks x 256 thr.
// OUTPUT ORDER IS RAW [B,H,S,d] CONTIGUOUS (torch .view(B,S,512) is a reinterpret).
__global__ __launch_bounds__(256)
void reduce_partials(const unsigned int* __restrict__ part, float* __restrict__ out) {
  const size_t tid = (size_t)blockIdx.x * 256 + threadIdx.x;   // 2,097,152 total
  const unsigned int d  = (unsigned int)(tid & 63);
  const unsigned int h  = (unsigned int)((tid >> 6) & 7);
  const unsigned int sp = (unsigned int)((tid >> 9) & 2047);
  const unsigned int b  = (unsigned int)(tid >> 20);
  float lo = 0.f, hi = 0.f;
#pragma unroll
  for (int tcc = 0; tcc < 4; ++tcc) {
    unsigned int v = part[(((size_t)(tcc * 2 + b) * NHEAD + h) * (S_LEN / 2) + sp) * HEADD + d];
    lo += __uint_as_float(v << 16);
    hi += __uint_as_float(v & 0xffff0000u);
  }
  float* o = out + (((size_t)(b * NHEAD + h)) * S_LEN + 2 * sp) * HEADD + d;
  o[0]     = lo;
  o[HEADD] = hi;   // s = 2*sp + 1
}

// ---------------- zero-workspace fallback (round-1 kernel, known correct) ----------------
__global__ __launch_bounds__(512, 2)
void attn_fallback(const float* __restrict__ Qg0, const float* __restrict__ Kg0,
                   const float* __restrict__ Vg0, float* __restrict__ Og0) {
  __shared__ __align__(16) unsigned short Klds[NHEAD][32][72];
  __shared__ __align__(16) unsigned short Vlds[NHEAD][HEADD][40];
  __shared__ __align__(16) unsigned short EA2[NHEAD][64][40];
  const int tid = threadIdx.x, h = tid >> 6, lane = tid & 63, quad = lane >> 4, l15 = lane & 15;
  const int b = blockIdx.x >> 6, s0 = (blockIdx.x & 63) * 64;
  const float* Qg = Qg0 + ((size_t)(b * NHEAD + h)) * S_LEN * HEADD;
  const float* Kg = Kg0 + ((size_t)(b * NHEAD + h)) * HEADD * S_LEN;
  const float* Vg = Vg0 + ((size_t)(b * NHEAD + h)) * S_LEN * HEADD;
  float* Og = Og0 + ((size_t)(b * NHEAD + h)) * S_LEN * HEADD;
  const float SC = 0.04419417382415922f;
  short8 qf[4][2];
#pragma unroll
  for (int ss = 0; ss < 4; ++ss)
#pragma unroll
    for (int kk = 0; kk < 2; ++kk) {
      const float* p = Qg + (size_t)(s0 + ss * 16 + l15) * HEADD + kk * 32 + quad * 8;
      float4v a0 = *(const float4v*)p; float4v a1 = *(const float4v*)(p + 4);
      short8 f;
      f[0] = (short)f2bf(a0[0]); f[1] = (short)f2bf(a0[1]); f[2] = (short)f2bf(a0[2]); f[3] = (short)f2bf(a0[3]);
      f[4] = (short)f2bf(a1[0]); f[5] = (short)f2bf(a1[1]); f[6] = (short)f2bf(a1[2]); f[7] = (short)f2bf(a1[3]);
      qf[ss][kk] = f;
    }
  float4v acc[4][4];
#pragma unroll
  for (int ss = 0; ss < 4; ++ss)
#pragma unroll
    for (int ds = 0; ds < 4; ++ds) acc[ss][ds] = (float4v){0.f, 0.f, 0.f, 0.f};
  const int koct = lane >> 3, kt4 = (lane & 7) * 4, vdq = lane & 15, vtg = lane >> 4;
  const int s_sm = tid >> 3, t4_sm = (tid & 7) * 4;
  for (int it = 0; it < S_LEN / 32; ++it) {
    const int t0 = it * 32;
    {
      float buf[8][4];
#pragma unroll
      for (int j = 0; j < 8; ++j) {
        float4v v = *(const float4v*)(Kg + (size_t)(koct * 8 + j) * S_LEN + t0 + kt4);
        buf[j][0] = v[0]; buf[j][1] = v[1]; buf[j][2] = v[2]; buf[j][3] = v[3];
      }
#pragma unroll
      for (int c = 0; c < 4; ++c) {
        short8 f;
#pragma unroll
        for (int j = 0; j < 8; ++j) f[j] = (short)f2bf(buf[j][c]);
        *(short8*)&Klds[h][kt4 + c][koct * 8] = f;
      }
    }
    {
      float buf[8][4];
#pragma unroll
      for (int j = 0; j < 8; ++j) {
        float4v v = *(const float4v*)(Vg + (size_t)(t0 + vtg * 8 + j) * HEADD + vdq * 4);
        buf[j][0] = v[0]; buf[j][1] = v[1]; buf[j][2] = v[2]; buf[j][3] = v[3];
      }
#pragma unroll
      for (int c = 0; c < 4; ++c) {
        short8 f;
#pragma unroll
        for (int j = 0; j < 8; ++j) f[j] = (short)f2bf(buf[j][c]);
        *(short8*)&Vlds[h][vdq * 4 + c][vtg * 8] = f;
      }
    }
    __syncthreads();
#pragma unroll
    for (int ts = 0; ts < 2; ++ts) {
      short8 kf0 = *(const short8*)&Klds[h][ts * 16 + l15][quad * 8];
      short8 kf1 = *(const short8*)&Klds[h][ts * 16 + l15][32 + quad * 8];
#pragma unroll
      for (int ss = 0; ss < 4; ++ss) {
        float4v e = (float4v){0.f, 0.f, 0.f, 0.f};
        e = __builtin_amdgcn_mfma_f32_16x16x32_bf16(qf[ss][0], kf0, e, 0, 0, 0);
        e = __builtin_amdgcn_mfma_f32_16x16x32_bf16(qf[ss][1], kf1, e, 0, 0, 0);
#pragma unroll
        for (int r = 0; r < 4; ++r)
          EA2[h][ss * 16 + quad * 4 + r][ts * 16 + l15] = __half_as_ushort(__float2half(e[r] * SC));
      }
    }
    __syncthreads();
    {
      float ev[8][4];
#pragma unroll
      for (int hh = 0; hh < 8; ++hh) {
        unsigned long long u = *(const unsigned long long*)&EA2[hh][s_sm][t4_sm];
        ev[hh][0] = __half2float(__ushort_as_half((unsigned short)u));
        ev[hh][1] = __half2float(__ushort_as_half((unsigned short)(u >> 16)));
        ev[hh][2] = __half2float(__ushort_as_half((unsigned short)(u >> 32)));
        ev[hh][3] = __half2float(__ushort_as_half((unsigned short)(u >> 48)));
      }
#pragma unroll
      for (int c = 0; c < 4; ++c) {
        float m = ev[0][c];
#pragma unroll
        for (int hh = 1; hh < 8; ++hh) m = fmaxf(m, ev[hh][c]);
        float sum = 0.f;
#pragma unroll
        for (int hh = 0; hh < 8; ++hh) { float x = __expf(ev[hh][c] - m); ev[hh][c] = x; sum += x; }
        float inv = __builtin_amdgcn_rcpf(sum);
#pragma unroll
        for (int hh = 0; hh < 8; ++hh) ev[hh][c] *= inv;
      }
#pragma unroll
      for (int hh = 0; hh < 8; ++hh) {
        unsigned short u0 = f2bf(ev[hh][0]), u1 = f2bf(ev[hh][1]), u2 = f2bf(ev[hh][2]), u3 = f2bf(ev[hh][3]);
        unsigned long long w = (unsigned long long)u0 | ((unsigned long long)u1 << 16) |
                               ((unsigned long long)u2 << 32) | ((unsigned long long)u3 << 48);
        *(unsigned long long*)&EA2[hh][s_sm][t4_sm] = w;
      }
    }
    __syncthreads();
    {
      short8 af[4], vf[4];
#pragma unroll
      for (int ss = 0; ss < 4; ++ss) af[ss] = *(const short8*)&EA2[h][ss * 16 + l15][quad * 8];
#pragma unroll
      for (int ds = 0; ds < 4; ++ds) vf[ds] = *(const short8*)&Vlds[h][ds * 16 + l15][quad * 8];
#pragma unroll
      for (int ss = 0; ss < 4; ++ss)
#pragma unroll
        for (int ds = 0; ds < 4; ++ds)
          acc[ss][ds] = __builtin_amdgcn_mfma_f32_16x16x32_bf16(af[ss], vf[ds], acc[ss][ds], 0, 0, 0);
    }
    __syncthreads();
  }
#pragma unroll
  for (int ss = 0; ss < 4; ++ss)
#pragma unroll
    for (int ds = 0; ds < 4; ++ds)
#pragma unroll
      for (int r = 0; r < 4; ++r)
        Og[(size_t)(s0 + ss * 16 + quad * 4 + r) * HEADD + ds * 16 + l15] = acc[ss][ds][r];
}

extern "C" void kernel_launch(void* const* d_in, const int* in_sizes, int n_in,
                              void* d_out, int out_size, void* d_ws, size_t ws_size,
                              hipStream_t stream) {
  const float* Q = (const float*)d_in[0];
  const float* K = (const float*)d_in[1];
  const float* V = (const float*)d_in[2];
  float* O = (float*)d_out;

  if (ws_size >= WS_FULL) {
    unsigned short* Kt = (unsigned short*)d_ws;
    unsigned short* Vt = (unsigned short*)((char*)d_ws + VT_OFF);
    unsigned int* part = (unsigned int*)((char*)d_ws + PART_OFF);
    hipLaunchKernelGGL(prepass_cvt, dim3(1024), dim3(256), 0, stream, K, V, Kt, Vt);
    hipLaunchKernelGGL(attn_main, dim3(2048), dim3(512), 0, stream, Q, Kt, Vt, part);
    hipLaunchKernelGGL(reduce_partials, dim3(8192), dim3(256), 0, stream, part, O);
  } else {
    hipLaunchKernelGGL(attn_fallback, dim3(128), dim3(512), 0, stream, Q, K, V, O);
  }
}

// Round 6
// 358.860 us; speedup vs baseline: 4.1210x; 1.5570x over previous
//
#include <hip/hip_runtime.h>
#include <hip/hip_fp16.h>
#include <cmath>

// B=2, H=8, S=4096, d=64; fp32 in/out.
// e = (Q@K)/sqrt(512); a = softmax over HEADS; o = a@V.
//
// R13: chain-count reduction. Empirical law from R7/R10/R12: attn_main time ~
// (barrier-chains per CU) x (per-tile latency). R7=128 chains->278us,
// R12=256->498us. R13: BM=32, BN=64, TSPLIT=4 -> 1024 blocks x 16 tiles =
// 64 chains/CU, 32 MFMAs per tile per wave (2x R7's work per chain).
//  - swapped QK^T + kperm (R11/R12-verified): lane holds f32 scores at
//    (s=s0+ss*16+l15, t=ts*32+8q+j) == PV A-frag layout. exp2 in-register.
//  - exps packed bf16 pairs (pkbf) -> 8x ds_write_b64 into EWp[h][32][34]
//    (pitch 34 u32 -> ~4-way banks). 512 thr sum 4 slots each (8x b64 reads)
//    -> Zb[2][32][68] f32. PV normalizes CARRIED packed exps vs Zb[prev].
//  - 2 barriers/tile, single EW buffer (all write/read pairs barrier-checked).
//  - LDS 52.2KB; persistent regs ~80 (acc32+qf16+pk32); launch_bounds(512,4).
// R11 lesson: no LDS atomics. R12 lesson: never raise chains/CU.
#define S_LEN 4096
#define NHEAD 8
#define HEADD 64
#define BM 32
#define BN 64
#define TSPLIT 4
#define TCHUNK (S_LEN / TSPLIT)      // 1024 keys per combo
#define NTILE (TCHUNK / BN)          // 16 iterations
#define KPRE 0.0637588696f           // (1/sqrt(512)) * log2(e)

#define KT_BYTES (2ull * NHEAD * S_LEN * HEADD * 2)        // 8,388,608 bf16 K^T [t][k]
#define VT_OFF   KT_BYTES
#define PART_OFF (2 * KT_BYTES)                             // 16,777,216
#define PART_BYTES (8ull * NHEAD * (S_LEN / 2) * HEADD * 4) // 33,554,432 (8 combos)
#define WS_FULL  (PART_OFF + PART_BYTES)                    // 50,331,648

typedef __attribute__((ext_vector_type(8))) short        short8;
typedef __attribute__((ext_vector_type(4))) float        float4v;
typedef __attribute__((ext_vector_type(2))) unsigned int uint2v;

__device__ __forceinline__ unsigned short f2bf(float f) {  // fp32 -> bf16 RNE
  unsigned int u = __float_as_uint(f);
  u += 0x7FFFu + ((u >> 16) & 1u);
  return (unsigned short)(u >> 16);
}

__device__ __forceinline__ unsigned int pkbf(float lo, float hi) {  // 2xfp32 -> packed bf16
  return __builtin_amdgcn_perm(__float_as_uint(hi) + 0x8000u,
                               __float_as_uint(lo) + 0x8000u, 0x07060302u);
}

// ---------------- pre-pass: LDS-free, float4 reads, in-register 8x4 transpose,
// b128 global writes. 1024 blocks x 256 thr (512 K-blocks, 512 V-blocks).
// K [bh,64,4096] f32 -> Kt [bh,4096,64] bf16*KPRE ; V [bh,4096,64] f32 -> Vt [bh,64,4096] bf16
__global__ __launch_bounds__(256)
void prepass_cvt(const float* __restrict__ K, const float* __restrict__ V,
                 unsigned short* __restrict__ Kt, unsigned short* __restrict__ Vt) {
  const int tid  = threadIdx.x;
  const int wave = tid >> 6, lane = tid & 63;
  const int isV  = blockIdx.x >> 9;
  const int idx  = blockIdx.x & 511;
  const int bh   = idx >> 5;                       // 16 bh
  const int t0   = (idx & 31) * 128 + wave * 32;   // block covers 128 t; wave covers 32 t
  if (!isV) {
    const float* in = K + (size_t)bh * HEADD * S_LEN;       // [k][t]
    unsigned short* out = Kt + (size_t)bh * S_LEN * HEADD;  // [t][k]
    const int koct = lane >> 3;          // k = koct*8 + j
    const int kt4  = (lane & 7) * 4;     // 4 t per lane
    float buf[8][4];
#pragma unroll
    for (int j = 0; j < 8; ++j) {
      float4v v = *(const float4v*)(in + (size_t)(koct * 8 + j) * S_LEN + t0 + kt4);
      buf[j][0] = v[0]; buf[j][1] = v[1]; buf[j][2] = v[2]; buf[j][3] = v[3];
    }
#pragma unroll
    for (int c = 0; c < 4; ++c) {
      short8 f;
#pragma unroll
      for (int j = 0; j < 8; ++j) f[j] = (short)f2bf(buf[j][c] * KPRE);
      *(short8*)(out + (size_t)(t0 + kt4 + c) * HEADD + koct * 8) = f;
    }
  } else {
    const float* in = V + (size_t)bh * S_LEN * HEADD;       // [t][d]
    unsigned short* out = Vt + (size_t)bh * HEADD * S_LEN;  // [d][t]
    const int vdq = lane & 15;           // d = vdq*4 + c
    const int vtg = lane >> 4;           // t = t0 + vtg*8 + j
    float buf[8][4];
#pragma unroll
    for (int j = 0; j < 8; ++j) {
      float4v v = *(const float4v*)(in + (size_t)(t0 + vtg * 8 + j) * HEADD + vdq * 4);
      buf[j][0] = v[0]; buf[j][1] = v[1]; buf[j][2] = v[2]; buf[j][3] = v[3];
    }
#pragma unroll
    for (int c = 0; c < 4; ++c) {
      short8 f;
#pragma unroll
      for (int j = 0; j < 8; ++j) f[j] = (short)f2bf(buf[j][c]);
      *(short8*)(out + (size_t)(vdq * 4 + c) * S_LEN + t0 + vtg * 8) = f;
    }
  }
}

// ---------------- main: 1024 blocks x 512 thr (8 waves, wave=head), BM=32, BN=64.
// combo = blockIdx&7: XCD-pinned (b,tc); each XCD's L2 holds its 2MB K/V slice.
__global__ __launch_bounds__(512, 4)
void attn_main(const float* __restrict__ Q, const unsigned short* __restrict__ Kt,
               const unsigned short* __restrict__ Vt, unsigned int* __restrict__ part) {
  // EWp: packed bf16 exp pairs, [h][s][tp], pitch 34 u32 (b64 ~4-way banks).
  // Zb:  f32 head-sums, [buf][s][t], pitch 68.
  __shared__ __align__(16) unsigned int EWp[NHEAD][BM][34];   // 34,816 B
  __shared__ __align__(16) float        Zb[2][BM][68];        // 17,408 B

  const int tid  = threadIdx.x;
  const int h    = tid >> 6;
  const int lane = tid & 63;
  const int quad = lane >> 4;
  const int l15  = lane & 15;
  const int combo = blockIdx.x & 7;
  const int b  = combo & 1;
  const int tc = combo >> 1;
  const int s0 = (blockIdx.x >> 3) * BM;
  const int tbase = tc * TCHUNK;
  // A-frag row perm: score slot (quad, grp*4+r) holds t-offset 8*quad + grp*4+r
  const int kperm = ((l15 >> 2) << 3) + (l15 & 3);
  const int s_r = tid >> 4;            // sum-phase row 0..31
  const int g   = tid & 15;            // sum-phase t-group (t = 4g..4g+3)

  const float* Qg = Q + (size_t)(b * NHEAD + h) * S_LEN * HEADD;
  const unsigned short* Kth = Kt + (size_t)(b * NHEAD + h) * S_LEN * HEADD;  // [t][k]
  const unsigned short* Vth = Vt + (size_t)(b * NHEAD + h) * HEADD * S_LEN;  // [d][t]

  // Q B-frags: n=l15 (s-row = s0+ss*16+l15), k = kk*32 + quad*8 + j
  short8 qf[2][2];
#pragma unroll
  for (int ss = 0; ss < 2; ++ss)
#pragma unroll
    for (int kk = 0; kk < 2; ++kk) {
      const float* p = Qg + (size_t)(s0 + ss * 16 + l15) * HEADD + kk * 32 + quad * 8;
      float4v a0 = *(const float4v*)p;
      float4v a1 = *(const float4v*)(p + 4);
      short8 f;
      f[0] = (short)f2bf(a0[0]); f[1] = (short)f2bf(a0[1]);
      f[2] = (short)f2bf(a0[2]); f[3] = (short)f2bf(a0[3]);
      f[4] = (short)f2bf(a1[0]); f[5] = (short)f2bf(a1[1]);
      f[6] = (short)f2bf(a1[2]); f[7] = (short)f2bf(a1[3]);
      qf[ss][kk] = f;
    }

  // acc[ss][df] = o[s = s0+ss*16+quad*4+r][d = df*16+l15]
  float4v acc[2][4];
#pragma unroll
  for (int ss = 0; ss < 2; ++ss)
#pragma unroll
    for (int df = 0; df < 4; ++df)
      acc[ss][df] = (float4v){0.f, 0.f, 0.f, 0.f};

  unsigned int pkP[2][2][4];   // prev tile's packed exps [ss][ts][pair]

  for (int it = 0; it < NTILE; ++it) {
    const int t0 = tbase + it * BN;
    unsigned int pkC[2][2][4];

    // ---- phase A: QK^T + exp2 + packed write to EWp ----
#pragma unroll
    for (int ts = 0; ts < 2; ++ts) {
      const unsigned short* Kp = Kth + (size_t)(t0 + ts * 32 + kperm) * HEADD + quad * 8;
      short8 k00 = *(const short8*)(Kp);
      short8 k01 = *(const short8*)(Kp + 32);
      short8 k10 = *(const short8*)(Kp + 4 * HEADD);
      short8 k11 = *(const short8*)(Kp + 4 * HEADD + 32);
#pragma unroll
      for (int ss = 0; ss < 2; ++ss) {
        float4v e0 = (float4v){0.f, 0.f, 0.f, 0.f};
        float4v e1 = (float4v){0.f, 0.f, 0.f, 0.f};
        e0 = __builtin_amdgcn_mfma_f32_16x16x32_bf16(k00, qf[ss][0], e0, 0, 0, 0);
        e0 = __builtin_amdgcn_mfma_f32_16x16x32_bf16(k01, qf[ss][1], e0, 0, 0, 0);
        e1 = __builtin_amdgcn_mfma_f32_16x16x32_bf16(k10, qf[ss][0], e1, 0, 0, 0);
        e1 = __builtin_amdgcn_mfma_f32_16x16x32_bf16(k11, qf[ss][1], e1, 0, 0, 0);
        float p0 = exp2f(e0[0]), p1 = exp2f(e0[1]), p2 = exp2f(e0[2]), p3 = exp2f(e0[3]);
        float p4 = exp2f(e1[0]), p5 = exp2f(e1[1]), p6 = exp2f(e1[2]), p7 = exp2f(e1[3]);
        pkC[ss][ts][0] = pkbf(p0, p1);   // t = ts*32+8q+{0,1}
        pkC[ss][ts][1] = pkbf(p2, p3);   // +{2,3}
        pkC[ss][ts][2] = pkbf(p4, p5);   // +{4,5}
        pkC[ss][ts][3] = pkbf(p6, p7);   // +{6,7}
        unsigned int* ew = &EWp[h][ss * 16 + l15][16 * ts + 4 * quad];
        *(uint2v*)(ew)     = (uint2v){pkC[ss][ts][0], pkC[ss][ts][1]};
        *(uint2v*)(ew + 2) = (uint2v){pkC[ss][ts][2], pkC[ss][ts][3]};
      }
    }
    __syncthreads();

    // ---- phase B: V/z prefetch, head-sum -> Zb[p], PV(it-1) vs Zb[p^1] ----
    {
      const int p = it & 1;
      // head-sum: this thread owns slots (s_r, t = 4g..4g+3)
      float z0 = 0.f, z1 = 0.f, z2 = 0.f, z3 = 0.f;
#pragma unroll
      for (int hh = 0; hh < 8; ++hh) {
        uint2v v = *(const uint2v*)&EWp[hh][s_r][2 * g];
        z0 += __uint_as_float(v.x << 16); z1 += __uint_as_float(v.x & 0xffff0000u);
        z2 += __uint_as_float(v.y << 16); z3 += __uint_as_float(v.y & 0xffff0000u);
      }
      *(float4v*)&Zb[p][s_r][4 * g] = (float4v){z0, z1, z2, z3};

      if (it) {
        const int pp  = p ^ 1;
        const int tp0 = t0 - BN;
#pragma unroll
        for (int ts = 0; ts < 2; ++ts) {
          short8 vf[4];
#pragma unroll
          for (int df = 0; df < 4; ++df)
            vf[df] = *(const short8*)(Vth + (size_t)(df * 16 + l15) * S_LEN
                                      + tp0 + ts * 32 + quad * 8);
#pragma unroll
          for (int ss = 0; ss < 2; ++ss) {
            const float* zr = &Zb[pp][ss * 16 + l15][ts * 32 + quad * 8];
            float4v za = *(const float4v*)zr;
            float4v zb2 = *(const float4v*)(zr + 4);
            short8 pf;
            unsigned int* pu = (unsigned int*)&pf;
            pu[0] = pkbf(__uint_as_float(pkP[ss][ts][0] << 16)         * __builtin_amdgcn_rcpf(za[0]),
                         __uint_as_float(pkP[ss][ts][0] & 0xffff0000u) * __builtin_amdgcn_rcpf(za[1]));
            pu[1] = pkbf(__uint_as_float(pkP[ss][ts][1] << 16)         * __builtin_amdgcn_rcpf(za[2]),
                         __uint_as_float(pkP[ss][ts][1] & 0xffff0000u) * __builtin_amdgcn_rcpf(za[3]));
            pu[2] = pkbf(__uint_as_float(pkP[ss][ts][2] << 16)         * __builtin_amdgcn_rcpf(zb2[0]),
                         __uint_as_float(pkP[ss][ts][2] & 0xffff0000u) * __builtin_amdgcn_rcpf(zb2[1]));
            pu[3] = pkbf(__uint_as_float(pkP[ss][ts][3] << 16)         * __builtin_amdgcn_rcpf(zb2[2]),
                         __uint_as_float(pkP[ss][ts][3] & 0xffff0000u) * __builtin_amdgcn_rcpf(zb2[3]));
#pragma unroll
            for (int df = 0; df < 4; ++df)
              acc[ss][df] = __builtin_amdgcn_mfma_f32_16x16x32_bf16(pf, vf[df], acc[ss][df], 0, 0, 0);
          }
        }
      }
#pragma unroll
      for (int ss = 0; ss < 2; ++ss)
#pragma unroll
        for (int ts = 0; ts < 2; ++ts)
#pragma unroll
          for (int i = 0; i < 4; ++i)
            pkP[ss][ts][i] = pkC[ss][ts][i];
    }
    __syncthreads();
  }

  // ---- epilogue: PV(NTILE-1) vs Zb[(NTILE-1)&1] ----
  {
    const int pp  = (NTILE - 1) & 1;
    const int tp0 = tbase + (NTILE - 1) * BN;
#pragma unroll
    for (int ts = 0; ts < 2; ++ts) {
      short8 vf[4];
#pragma unroll
      for (int df = 0; df < 4; ++df)
        vf[df] = *(const short8*)(Vth + (size_t)(df * 16 + l15) * S_LEN
                                  + tp0 + ts * 32 + quad * 8);
#pragma unroll
      for (int ss = 0; ss < 2; ++ss) {
        const float* zr = &Zb[pp][ss * 16 + l15][ts * 32 + quad * 8];
        float4v za = *(const float4v*)zr;
        float4v zb2 = *(const float4v*)(zr + 4);
        short8 pf;
        unsigned int* pu = (unsigned int*)&pf;
        pu[0] = pkbf(__uint_as_float(pkP[ss][ts][0] << 16)         * __builtin_amdgcn_rcpf(za[0]),
                     __uint_as_float(pkP[ss][ts][0] & 0xffff0000u) * __builtin_amdgcn_rcpf(za[1]));
        pu[1] = pkbf(__uint_as_float(pkP[ss][ts][1] << 16)         * __builtin_amdgcn_rcpf(za[2]),
                     __uint_as_float(pkP[ss][ts][1] & 0xffff0000u) * __builtin_amdgcn_rcpf(za[3]));
        pu[2] = pkbf(__uint_as_float(pkP[ss][ts][2] << 16)         * __builtin_amdgcn_rcpf(zb2[0]),
                     __uint_as_float(pkP[ss][ts][2] & 0xffff0000u) * __builtin_amdgcn_rcpf(zb2[1]));
        pu[3] = pkbf(__uint_as_float(pkP[ss][ts][3] << 16)         * __builtin_amdgcn_rcpf(zb2[2]),
                     __uint_as_float(pkP[ss][ts][3] & 0xffff0000u) * __builtin_amdgcn_rcpf(zb2[3]));
#pragma unroll
        for (int df = 0; df < 4; ++df)
          acc[ss][df] = __builtin_amdgcn_mfma_f32_16x16x32_bf16(pf, vf[df], acc[ss][df], 0, 0, 0);
      }
    }
  }

  // ---- partials: packed bf16 s-pairs, layout [combo(8)][h][sp(2048)][d(64)] ----
  unsigned int* pb = part + ((size_t)combo * NHEAD + h) * (2048ull * 64);
  const int spb = (s0 >> 1) + quad * 2;
#pragma unroll
  for (int ss = 0; ss < 2; ++ss)
#pragma unroll
    for (int df = 0; df < 4; ++df)
#pragma unroll
      for (int rp = 0; rp < 2; ++rp) {
        unsigned int ulo = __float_as_uint(acc[ss][df][rp * 2])     + 0x8000u;
        unsigned int uhi = __float_as_uint(acc[ss][df][rp * 2 + 1]) + 0x8000u;
        unsigned int pk  = __builtin_amdgcn_perm(uhi, ulo, 0x07060302u);
        pb[(size_t)(spb + ss * 8 + rp) * 64 + df * 16 + l15] = pk;
      }
}

// ---------------- reduce: sum 4 tc-partials (packed bf16 s-pairs) -> fp32 O ----------------
// part: [c=tc*2+b (8)][h (8)][sp (2048)][d (64)] u32. 8192 blocks x 256 thr.
// OUTPUT ORDER IS RAW [B,H,S,d] CONTIGUOUS (torch .view(B,S,512) is a reinterpret).
__global__ __launch_bounds__(256)
void reduce_partials(const unsigned int* __restrict__ part, float* __restrict__ out) {
  const size_t tid = (size_t)blockIdx.x * 256 + threadIdx.x;   // 2,097,152 total
  const unsigned int d  = (unsigned int)(tid & 63);
  const unsigned int h  = (unsigned int)((tid >> 6) & 7);
  const unsigned int sp = (unsigned int)((tid >> 9) & 2047);
  const unsigned int b  = (unsigned int)(tid >> 20);
  float lo = 0.f, hi = 0.f;
#pragma unroll
  for (int tcc = 0; tcc < 4; ++tcc) {
    unsigned int v = part[(((size_t)(tcc * 2 + b) * NHEAD + h) * (S_LEN / 2) + sp) * HEADD + d];
    lo += __uint_as_float(v << 16);
    hi += __uint_as_float(v & 0xffff0000u);
  }
  float* o = out + (((size_t)(b * NHEAD + h)) * S_LEN + 2 * sp) * HEADD + d;
  o[0]     = lo;
  o[HEADD] = hi;   // s = 2*sp + 1
}

// ---------------- zero-workspace fallback (round-1 kernel, known correct) ----------------
__global__ __launch_bounds__(512, 2)
void attn_fallback(const float* __restrict__ Qg0, const float* __restrict__ Kg0,
                   const float* __restrict__ Vg0, float* __restrict__ Og0) {
  __shared__ __align__(16) unsigned short Klds[NHEAD][32][72];
  __shared__ __align__(16) unsigned short Vlds[NHEAD][HEADD][40];
  __shared__ __align__(16) unsigned short EA2[NHEAD][64][40];
  const int tid = threadIdx.x, h = tid >> 6, lane = tid & 63, quad = lane >> 4, l15 = lane & 15;
  const int b = blockIdx.x >> 6, s0 = (blockIdx.x & 63) * 64;
  const float* Qg = Qg0 + ((size_t)(b * NHEAD + h)) * S_LEN * HEADD;
  const float* Kg = Kg0 + ((size_t)(b * NHEAD + h)) * HEADD * S_LEN;
  const float* Vg = Vg0 + ((size_t)(b * NHEAD + h)) * S_LEN * HEADD;
  float* Og = Og0 + ((size_t)(b * NHEAD + h)) * S_LEN * HEADD;
  const float SC = 0.04419417382415922f;
  short8 qf[4][2];
#pragma unroll
  for (int ss = 0; ss < 4; ++ss)
#pragma unroll
    for (int kk = 0; kk < 2; ++kk) {
      const float* p = Qg + (size_t)(s0 + ss * 16 + l15) * HEADD + kk * 32 + quad * 8;
      float4v a0 = *(const float4v*)p; float4v a1 = *(const float4v*)(p + 4);
      short8 f;
      f[0] = (short)f2bf(a0[0]); f[1] = (short)f2bf(a0[1]); f[2] = (short)f2bf(a0[2]); f[3] = (short)f2bf(a0[3]);
      f[4] = (short)f2bf(a1[0]); f[5] = (short)f2bf(a1[1]); f[6] = (short)f2bf(a1[2]); f[7] = (short)f2bf(a1[3]);
      qf[ss][kk] = f;
    }
  float4v acc[4][4];
#pragma unroll
  for (int ss = 0; ss < 4; ++ss)
#pragma unroll
    for (int ds = 0; ds < 4; ++ds) acc[ss][ds] = (float4v){0.f, 0.f, 0.f, 0.f};
  const int koct = lane >> 3, kt4 = (lane & 7) * 4, vdq = lane & 15, vtg = lane >> 4;
  const int s_sm = tid >> 3, t4_sm = (tid & 7) * 4;
  for (int it = 0; it < S_LEN / 32; ++it) {
    const int t0 = it * 32;
    {
      float buf[8][4];
#pragma unroll
      for (int j = 0; j < 8; ++j) {
        float4v v = *(const float4v*)(Kg + (size_t)(koct * 8 + j) * S_LEN + t0 + kt4);
        buf[j][0] = v[0]; buf[j][1] = v[1]; buf[j][2] = v[2]; buf[j][3] = v[3];
      }
#pragma unroll
      for (int c = 0; c < 4; ++c) {
        short8 f;
#pragma unroll
        for (int j = 0; j < 8; ++j) f[j] = (short)f2bf(buf[j][c]);
        *(short8*)&Klds[h][kt4 + c][koct * 8] = f;
      }
    }
    {
      float buf[8][4];
#pragma unroll
      for (int j = 0; j < 8; ++j) {
        float4v v = *(const float4v*)(Vg + (size_t)(t0 + vtg * 8 + j) * HEADD + vdq * 4);
        buf[j][0] = v[0]; buf[j][1] = v[1]; buf[j][2] = v[2]; buf[j][3] = v[3];
      }
#pragma unroll
      for (int c = 0; c < 4; ++c) {
        short8 f;
#pragma unroll
        for (int j = 0; j < 8; ++j) f[j] = (short)f2bf(buf[j][c]);
        *(short8*)&Vlds[h][vdq * 4 + c][vtg * 8] = f;
      }
    }
    __syncthreads();
#pragma unroll
    for (int ts = 0; ts < 2; ++ts) {
      short8 kf0 = *(const short8*)&Klds[h][ts * 16 + l15][quad * 8];
      short8 kf1 = *(const short8*)&Klds[h][ts * 16 + l15][32 + quad * 8];
#pragma unroll
      for (int ss = 0; ss < 4; ++ss) {
        float4v e = (float4v){0.f, 0.f, 0.f, 0.f};
        e = __builtin_amdgcn_mfma_f32_16x16x32_bf16(qf[ss][0], kf0, e, 0, 0, 0);
        e = __builtin_amdgcn_mfma_f32_16x16x32_bf16(qf[ss][1], kf1, e, 0, 0, 0);
#pragma unroll
        for (int r = 0; r < 4; ++r)
          EA2[h][ss * 16 + quad * 4 + r][ts * 16 + l15] = __half_as_ushort(__float2half(e[r] * SC));
      }
    }
    __syncthreads();
    {
      float ev[8][4];
#pragma unroll
      for (int hh = 0; hh < 8; ++hh) {
        unsigned long long u = *(const unsigned long long*)&EA2[hh][s_sm][t4_sm];
        ev[hh][0] = __half2float(__ushort_as_half((unsigned short)u));
        ev[hh][1] = __half2float(__ushort_as_half((unsigned short)(u >> 16)));
        ev[hh][2] = __half2float(__ushort_as_half((unsigned short)(u >> 32)));
        ev[hh][3] = __half2float(__ushort_as_half((unsigned short)(u >> 48)));
      }
#pragma unroll
      for (int c = 0; c < 4; ++c) {
        float m = ev[0][c];
#pragma unroll
        for (int hh = 1; hh < 8; ++hh) m = fmaxf(m, ev[hh][c]);
        float sum = 0.f;
#pragma unroll
        for (int hh = 0; hh < 8; ++hh) { float x = __expf(ev[hh][c] - m); ev[hh][c] = x; sum += x; }
        float inv = __builtin_amdgcn_rcpf(sum);
#pragma unroll
        for (int hh = 0; hh < 8; ++hh) ev[hh][c] *= inv;
      }
#pragma unroll
      for (int hh = 0; hh < 8; ++hh) {
        unsigned short u0 = f2bf(ev[hh][0]), u1 = f2bf(ev[hh][1]), u2 = f2bf(ev[hh][2]), u3 = f2bf(ev[hh][3]);
        unsigned long long w = (unsigned long long)u0 | ((unsigned long long)u1 << 16) |
                               ((unsigned long long)u2 << 32) | ((unsigned long long)u3 << 48);
        *(unsigned long long*)&EA2[hh][s_sm][t4_sm] = w;
      }
    }
    __syncthreads();
    {
      short8 af[4], vf[4];
#pragma unroll
      for (int ss = 0; ss < 4; ++ss) af[ss] = *(const short8*)&EA2[h][ss * 16 + l15][quad * 8];
#pragma unroll
      for (int ds = 0; ds < 4; ++ds) vf[ds] = *(const short8*)&Vlds[h][ds * 16 + l15][quad * 8];
#pragma unroll
      for (int ss = 0; ss < 4; ++ss)
#pragma unroll
        for (int ds = 0; ds < 4; ++ds)
          acc[ss][ds] = __builtin_amdgcn_mfma_f32_16x16x32_bf16(af[ss], vf[ds], acc[ss][ds], 0, 0, 0);
    }
    __syncthreads();
  }
#pragma unroll
  for (int ss = 0; ss < 4; ++ss)
#pragma unroll
    for (int ds = 0; ds < 4; ++ds)
#pragma unroll
      for (int r = 0; r < 4; ++r)
        Og[(size_t)(s0 + ss * 16 + quad * 4 + r) * HEADD + ds * 16 + l15] = acc[ss][ds][r];
}

extern "C" void kernel_launch(void* const* d_in, const int* in_sizes, int n_in,
                              void* d_out, int out_size, void* d_ws, size_t ws_size,
                              hipStream_t stream) {
  const float* Q = (const float*)d_in[0];
  const float* K = (const float*)d_in[1];
  const float* V = (const float*)d_in[2];
  float* O = (float*)d_out;

  if (ws_size >= WS_FULL) {
    unsigned short* Kt = (unsigned short*)d_ws;
    unsigned short* Vt = (unsigned short*)((char*)d_ws + VT_OFF);
    unsigned int* part = (unsigned int*)((char*)d_ws + PART_OFF);
    hipLaunchKernelGGL(prepass_cvt, dim3(1024), dim3(256), 0, stream, K, V, Kt, Vt);
    hipLaunchKernelGGL(attn_main, dim3(1024), dim3(512), 0, stream, Q, Kt, Vt, part);
    hipLaunchKernelGGL(reduce_partials, dim3(8192), dim3(256), 0, stream, part, O);
  } else {
    hipLaunchKernelGGL(attn_fallback, dim3(128), dim3(512), 0, stream, Q, K, V, O);
  }
}